// Round 14
// baseline (4135.056 us; speedup 1.0000x reference)
//
#include <hip/hip_runtime.h>
#include <math.h>

#define L 50
#define ML 64
#define VOCAB 32000
#define EMBED 1024
#define HID 1024
#define HH 512
#define TOT (VOCAB+ML)
#define NPART 501

// workspace layout (float offsets)
#define WS_ENC_GATES 0        // [2][4096]
#define WS_C_ENC     8192     // [2][1024]
#define WS_ENC_OUTS  10240    // [64][1024]
#define WS_COPY_ENC  75776    // [64][1024]
#define WS_H_DEC     141312   // [2][1024]
#define WS_C_DEC     143360   // [2][1024]
#define WS_X_DEC     145408   // [3072]
#define WS_DGATES    148480   // [4096]
#define WS_LOGITS    152576   // [32064]
#define WS_PARTS     184640   // [501*4] {lmax,sumexp,bestkey,bestidx}
#define WS_ATTW      186688   // [64] attn weights (final, softmaxed on fast path)
#define WS_PC        186752   // [64] selective-read weights
#define WS_ACT       186816   // [1] action
#define WS_G         186880   // [8192][64]: rows 0..4095 = G_sel, 4096..8191 = G_att
#define WS_G_END     (186880+8192*64)          // 711168
#define WS_PREG      711168   // [50][4096] encoder input-side pregates
#define WS_PREG_END  (711168+50*4096)          // 915968
#define WS_AH        915968   // [64] attn h-part logits
#define WS_P         916032   // [32000][64] attn emb-part logits
#define WS_P_END     (916032+32000*64)         // 2964032
#define WS_TICK      2964032  // [64] ints: per-step tickets
#define WS_END3      (2964032+64)

__device__ __forceinline__ float wred_sum(float v){
  #pragma unroll
  for(int o=32;o;o>>=1) v += __shfl_xor(v,o,64);
  return v;
}
__device__ __forceinline__ float wred_max(float v){
  #pragma unroll
  for(int o=32;o;o>>=1) v = fmaxf(v,__shfl_xor(v,o,64));
  return v;
}
__device__ __forceinline__ float sigm(float x){ return 1.0f/(1.0f+__expf(-x)); }
__device__ __forceinline__ float d4(float4 a, float4 b){ return a.x*b.x + a.y*b.y + a.z*b.z + a.w*b.w; }

// ================= encoder pregates, barrier-free + next-row prefetch =================
__global__ __launch_bounds__(256) void k_enc_pre2(
  const int* __restrict__ xt, const float* __restrict__ emb,
  const float* __restrict__ Wih_f, const float* __restrict__ bih_f, const float* __restrict__ bhh_f,
  const float* __restrict__ Wih_b, const float* __restrict__ bih_b, const float* __restrict__ bhh_b,
  float* __restrict__ ws)
{
  __shared__ int toks[L];
  const int tid=threadIdx.x, b=blockIdx.x, wave=tid>>6, lane=tid&63;
  float* pg = ws + WS_PREG;
  if(tid<L) toks[tid]=xt[tid];
  float4 wih[2][4]; float bias[2];
  #pragma unroll
  for(int rr=0;rr<2;rr++){
    int r=b*8+wave*2+rr; bool isF=(r<2048); int rl=isF?r:(r-2048);
    const float* wp=(isF?Wih_f:Wih_b)+(size_t)rl*EMBED;
    #pragma unroll
    for(int c4=0;c4<4;c4++) wih[rr][c4]=*(const float4*)(wp+c4*256+lane*4);
    bias[rr]= isF?(bih_f[rl]+bhh_f[rl]):(bih_b[rl]+bhh_b[rl]);
  }
  __syncthreads();
  const float* er0 = emb + (size_t)toks[0]*EMBED;
  float4 e0=*(const float4*)(er0      +lane*4);
  float4 e1=*(const float4*)(er0+256  +lane*4);
  float4 e2=*(const float4*)(er0+512  +lane*4);
  float4 e3=*(const float4*)(er0+768  +lane*4);
  for(int t=0;t<L;t++){
    int tn = (t+1<L)? t+1 : t;
    const float* en = emb + (size_t)toks[tn]*EMBED;
    float4 n0=*(const float4*)(en      +lane*4);
    float4 n1=*(const float4*)(en+256  +lane*4);
    float4 n2=*(const float4*)(en+512  +lane*4);
    float4 n3=*(const float4*)(en+768  +lane*4);
    #pragma unroll
    for(int rr=0;rr<2;rr++){
      int r=b*8+wave*2+rr;
      float acc = d4(wih[rr][0],e0)+d4(wih[rr][1],e1)+d4(wih[rr][2],e2)+d4(wih[rr][3],e3);
      acc=wred_sum(acc);
      if(lane==0) pg[(size_t)t*4096+r]=acc+bias[rr];
    }
    e0=n0; e1=n1; e2=n2; e3=n3;
  }
}

// ================= encoder recurrent step =================
__global__ __launch_bounds__(256) void k_enc_rec(
  const float* __restrict__ Whh_f, const float* __restrict__ Whh_b,
  float* __restrict__ ws, int t)
{
  __shared__ __align__(16) float h_lds[1024];
  const int tid=threadIdx.x, b=blockIdx.x, wave=tid>>6, lane=tid&63;
  float* gates   = ws + WS_ENC_GATES;
  float* c_enc   = ws + WS_C_ENC;
  float* enc_outs= ws + WS_ENC_OUTS;
  const float* pg = ws + WS_PREG + (size_t)t*4096;
  if(t>0){
    const float* gp = gates + ((t-1)&1)*4096;
    const float* cp = c_enc + (t&1)*1024;
    float* cw = c_enc + ((t-1)&1)*1024;
    for(int u=tid;u<1024;u+=256){
      int base=(u<512)?0:2048, uu=(u<512)?u:(u-512);
      float ig=gp[base+uu], fg=gp[base+512+uu], gg=gp[base+1024+uu], og=gp[base+1536+uu];
      float cprev=(t==1)?0.0f:cp[u];
      float c=sigm(fg)*cprev+sigm(ig)*tanhf(gg);
      float h=sigm(og)*tanhf(c);
      h_lds[u]=h;
      if(b==0){ cw[u]=c; enc_outs[(size_t)(t-1)*1024+u]=h; }
    }
  }
  __syncthreads();
  float* gw = gates + (t&1)*4096;
  #pragma unroll
  for(int rr=0;rr<2;rr++){
    int r=b*8+wave*2+rr; bool isF=(r<2048); int rl=isF?r:(r-2048);
    if(t==0){
      if(lane==0) gw[r]=pg[r];
    } else {
      const float* hr=(isF?Whh_f:Whh_b)+(size_t)rl*HH;
      const float* hs=&h_lds[isF?0:512];
      float acc=0.0f;
      #pragma unroll
      for(int c2=0;c2<2;c2++){
        int m=c2*256+lane*4;
        acc += d4(*(const float4*)(hr+m), *(const float4*)(&hs[m]));
      }
      acc=wred_sum(acc);
      if(lane==0) gw[r]=pg[r]+acc;
    }
  }
}

// ================= fallback encoder step (round-4 proven) =================
__global__ __launch_bounds__(256) void k_enc_step(
  const int* __restrict__ xt, const float* __restrict__ emb,
  const float* __restrict__ Wih_f, const float* __restrict__ Whh_f,
  const float* __restrict__ bih_f, const float* __restrict__ bhh_f,
  const float* __restrict__ Wih_b, const float* __restrict__ Whh_b,
  const float* __restrict__ bih_b, const float* __restrict__ bhh_b,
  float* __restrict__ ws, int t)
{
  __shared__ __align__(16) float h_lds[1024];
  __shared__ __align__(16) float xe[1024];
  const int tid = threadIdx.x;
  float* gates   = ws + WS_ENC_GATES;
  float* c_enc   = ws + WS_C_ENC;
  float* enc_outs= ws + WS_ENC_OUTS;
  {
    const int tok = xt[t];
    const float* er = emb + (size_t)tok*EMBED;
    for(int j=tid;j<1024;j+=256) xe[j]=er[j];
  }
  if(t>0){
    const float* gp = gates + ((t-1)&1)*4096;
    const float* cp = c_enc + (t&1)*1024;
    float* cw = c_enc + ((t-1)&1)*1024;
    for(int u=tid;u<1024;u+=256){
      int base=(u<512)?0:2048, uu=(u<512)?u:(u-512);
      float ig=gp[base+uu], fg=gp[base+512+uu], gg=gp[base+1024+uu], og=gp[base+1536+uu];
      float cprev=(t==1)?0.0f:cp[u];
      float c=sigm(fg)*cprev+sigm(ig)*tanhf(gg);
      float h=sigm(og)*tanhf(c);
      h_lds[u]=h;
      if(blockIdx.x==0){ cw[u]=c; enc_outs[(size_t)(t-1)*1024+u]=h; }
    }
  }
  __syncthreads();
  float* gw = gates + (t&1)*4096;
  const int wave=tid>>6, lane=tid&63;
  for(int rr=0;rr<2;rr++){
    int r=blockIdx.x*8+wave*2+rr;
    bool isF=(r<2048); int rl=isF?r:(r-2048);
    const float* Wih=isF?Wih_f:Wih_b;
    const float* Whh=isF?Whh_f:Whh_b;
    float bias=isF?(bih_f[rl]+bhh_f[rl]):(bih_b[rl]+bhh_b[rl]);
    const float* wr=Wih+(size_t)rl*EMBED;
    float acc=0.0f;
    #pragma unroll
    for(int c4=0;c4<4;c4++){
      int m=c4*256+lane*4;
      acc += d4(*(const float4*)(wr+m), *(const float4*)(&xe[m]));
    }
    if(t>0){
      const float* hr=Whh+(size_t)rl*HH;
      const float* hs=&h_lds[isF?0:512];
      #pragma unroll
      for(int c2=0;c2<2;c2++){
        int m=c2*256+lane*4;
        acc += d4(*(const float4*)(hr+m), *(const float4*)(&hs[m]));
      }
    }
    acc=wred_sum(acc);
    if(lane==0) gw[r]=acc+bias;
  }
}

// ================= k_copy_final (round-5 proven) =================
__global__ __launch_bounds__(256) void k_copy_final(
  const float* __restrict__ emb,
  const float* __restrict__ copy_W, const float* __restrict__ copy_b,
  float* __restrict__ ws, float* __restrict__ out)
{
  __shared__ __align__(16) float hf[1024];
  const int tid=threadIdx.x, b=blockIdx.x, wave=tid>>6, lane=tid&63;
  float* gates = ws + WS_ENC_GATES;
  float* c_enc = ws + WS_C_ENC;
  float* enc_outs = ws + WS_ENC_OUTS;
  float* cenc = ws + WS_COPY_ENC;
  float* h_dec = ws + WS_H_DEC;
  float* c_dec = ws + WS_C_DEC;
  float* x_dec = ws + WS_X_DEC;
  {
    const float* gp = gates + ((L-1)&1)*4096;
    const float* cp = c_enc + ((L-2)&1)*1024;
    for(int u=tid;u<1024;u+=256){
      int base=(u<512)?0:2048, uu=(u<512)?u:(u-512);
      float ig=gp[base+uu], fg=gp[base+512+uu], gg=gp[base+1024+uu], og=gp[base+1536+uu];
      float c=sigm(fg)*cp[u]+sigm(ig)*tanhf(gg);
      float h=sigm(og)*tanhf(c);
      hf[u]=h;
      if(b==0){
        enc_outs[(size_t)(L-1)*1024+u]=h;
        h_dec[1024+u]=h;
        c_dec[1024+u]=c;
        out[u]=h;
      }
    }
    if(b==1) for(int j=tid;j<(ML-L)*1024;j+=256) enc_outs[(size_t)L*1024+j]=0.0f;
    if(b==2) for(int j=tid;j<1024;j+=256){
      x_dec[j]=emb[j];
      x_dec[1024+j]=0.0f;
      x_dec[2048+j]=0.0f;
    }
  }
  __syncthreads();
  int j = b*4 + wave;
  const float* wr = copy_W + (size_t)j*1024;
  float4 w0=*(const float4*)(wr+0*256+lane*4);
  float4 w1=*(const float4*)(wr+1*256+lane*4);
  float4 w2=*(const float4*)(wr+2*256+lane*4);
  float4 w3=*(const float4*)(wr+3*256+lane*4);
  float bj = copy_b[j];
  for(int k=0;k<L-1;k++){
    const float* er = enc_outs + (size_t)k*1024;
    float acc = d4(w0,*(const float4*)(er+0*256+lane*4))
              + d4(w1,*(const float4*)(er+1*256+lane*4))
              + d4(w2,*(const float4*)(er+2*256+lane*4))
              + d4(w3,*(const float4*)(er+3*256+lane*4));
    acc = wred_sum(acc);
    if(lane==0) cenc[(size_t)k*1024+j]=tanhf(acc+bj);
  }
  {
    float acc = d4(w0,*(const float4*)(&hf[0*256+lane*4]))
              + d4(w1,*(const float4*)(&hf[1*256+lane*4]))
              + d4(w2,*(const float4*)(&hf[2*256+lane*4]))
              + d4(w3,*(const float4*)(&hf[3*256+lane*4]));
    acc = wred_sum(acc);
    if(lane==0) cenc[(size_t)(L-1)*1024+j]=tanhf(acc+bj);
  }
  if(lane==0){
    float z=tanhf(0.0f+bj);
    for(int k=L;k<ML;k++) cenc[(size_t)k*1024+j]=z;
  }
}

// ================= k_gmat3: no-LDS, barrier-free, next-row prefetch =================
__global__ __launch_bounds__(256) void k_gmat3(const float* __restrict__ Wih_d, float* __restrict__ ws)
{
  const int tid=threadIdx.x, wave=tid>>6, lane=tid&63;
  const float* enc = ws + WS_ENC_OUTS;
  float* G = ws + WS_G;
  float4 w[4][4];
  int rg[4];
  #pragma unroll
  for(int q=0;q<4;q++){
    int r = blockIdx.x*16 + wave*4 + q;     // 0..8191
    rg[q]=r;
    const float* W = (r<4096) ? (Wih_d + (size_t)r*3072 + 1024)
                              : (Wih_d + (size_t)(r-4096)*3072 + 2048);
    #pragma unroll
    for(int c4=0;c4<4;c4++) w[q][c4]=*(const float4*)(W + c4*256 + lane*4);
  }
  const float* er0 = enc;
  float4 e0=*(const float4*)(er0      +lane*4);
  float4 e1=*(const float4*)(er0+256  +lane*4);
  float4 e2=*(const float4*)(er0+512  +lane*4);
  float4 e3=*(const float4*)(er0+768  +lane*4);
  for(int k=0;k<L;k++){
    int kn = (k+1<L)? k+1 : k;
    const float* en = enc + (size_t)kn*1024;
    float4 n0=*(const float4*)(en      +lane*4);
    float4 n1=*(const float4*)(en+256  +lane*4);
    float4 n2=*(const float4*)(en+512  +lane*4);
    float4 n3=*(const float4*)(en+768  +lane*4);
    #pragma unroll
    for(int q=0;q<4;q++){
      float acc = d4(w[q][0],e0)+d4(w[q][1],e1)+d4(w[q][2],e2)+d4(w[q][3],e3);
      acc=wred_sum(acc);
      if(lane==0) G[(size_t)rg[q]*64 + k]=acc;
    }
    e0=n0; e1=n1; e2=n2; e3=n3;
  }
  if(lane==0){
    #pragma unroll
    for(int q=0;q<4;q++)
      for(int kk=L;kk<64;kk++) G[(size_t)rg[q]*64 + kk]=0.0f;
  }
}

// ================= k_pmat5: tiled GEMM P = emb @ attn_W[:,0:1024]^T (round-13 proven) =================
__global__ __launch_bounds__(256) void k_pmat5(
  const float* __restrict__ emb, const float* __restrict__ attn_W, float* __restrict__ ws)
{
  __shared__ float e_lds[64][68];
  __shared__ float w_lds[64][68];
  const int tid=threadIdx.x;
  const int wq=tid>>4, rq=tid&15;
  float* P = ws + WS_P;
  const int w0 = blockIdx.x*64;
  float acc[4][4];
  #pragma unroll
  for(int i=0;i<4;i++)
    #pragma unroll
    for(int j=0;j<4;j++) acc[i][j]=0.0f;
  for(int kc=0;kc<16;kc++){
    __syncthreads();
    #pragma unroll
    for(int v=0;v<4;v++){
      int idx=(v*256+tid)*4;
      int row=idx>>6, col=idx&63;
      float4 te=*(const float4*)(emb    + (size_t)(w0+row)*EMBED + kc*64 + col);
      *(float4*)&e_lds[row][col]=te;
      float4 tw=*(const float4*)(attn_W + (size_t)row*2048      + kc*64 + col);
      *(float4*)&w_lds[row][col]=tw;
    }
    __syncthreads();
    #pragma unroll
    for(int k4=0;k4<16;k4++){
      float4 e4[4], w4[4];
      #pragma unroll
      for(int i=0;i<4;i++) e4[i]=*(const float4*)&e_lds[wq+i*16][k4*4];
      #pragma unroll
      for(int j=0;j<4;j++) w4[j]=*(const float4*)&w_lds[rq+j*16][k4*4];
      #pragma unroll
      for(int i=0;i<4;i++)
        #pragma unroll
        for(int j=0;j<4;j++){
          acc[i][j] += e4[i].x*w4[j].x;
          acc[i][j] += e4[i].y*w4[j].y;
          acc[i][j] += e4[i].z*w4[j].z;
          acc[i][j] += e4[i].w*w4[j].w;
        }
    }
  }
  #pragma unroll
  for(int i=0;i<4;i++)
    #pragma unroll
    for(int j=0;j<4;j++)
      P[(size_t)(w0+wq+i*16)*64 + rq+j*16] = acc[i][j];
}

// ================= k_fin16: finalize (fallback path) =================
__global__ __launch_bounds__(256) void k_fin16(
  const int* __restrict__ xt, const float* __restrict__ amask,
  const float* __restrict__ emb,
  const float* __restrict__ attn_W, const float* __restrict__ attn_b,
  float* __restrict__ ws, float* __restrict__ out, int t, int fin_only)
{
  __shared__ __align__(16) float dec_in[1024];
  __shared__ __align__(16) float hprev[1024];
  __shared__ float r_lm[256], r_sm[256], r_ky[256];
  __shared__ int r_ix[256];
  __shared__ float s_lmax, s_Z;
  __shared__ int s_act;
  const int tid=threadIdx.x, b=blockIdx.x, wave=tid>>6, lane=tid&63;
  float* h_dec=ws+WS_H_DEC;
  float* logits=ws+WS_LOGITS; float* parts=ws+WS_PARTS;
  float* attw_raw=ws+WS_ATTW; float* pcw=ws+WS_PC;
  {
    float lm=-INFINITY, sm=0.0f, ky=-INFINITY; int ix=0x7fffffff;
    for(int i=tid;i<NPART;i+=256){
      const float4 p = *(const float4*)(parts+(size_t)i*4);
      float plm=p.x, psm=p.y, pky=p.z; int pix=__float_as_int(p.w);
      if(plm>lm){ sm = sm*__expf(lm-plm)+psm; lm=plm; }
      else sm += psm*__expf(plm-lm);
      if(pky>ky || (pky==ky && pix<ix)){ ky=pky; ix=pix; }
    }
    r_lm[tid]=lm; r_sm[tid]=sm; r_ky[tid]=ky; r_ix[tid]=ix;
    __syncthreads();
    for(int s=128;s;s>>=1){
      if(tid<s){
        float blm=r_lm[tid+s], bsm=r_sm[tid+s];
        float alm=r_lm[tid], a_sm=r_sm[tid];
        if(blm>alm){ r_sm[tid]=a_sm*__expf(alm-blm)+bsm; r_lm[tid]=blm; }
        else r_sm[tid]=a_sm+bsm*__expf(blm-alm);
        float bky=r_ky[tid+s]; int bix=r_ix[tid+s];
        if(bky>r_ky[tid] || (bky==r_ky[tid] && bix<r_ix[tid])){ r_ky[tid]=bky; r_ix[tid]=bix; }
      }
      __syncthreads();
    }
    if(tid==0){
      float lmax=r_lm[0]; float Z=r_sm[0];
      float bky=r_ky[0];
      int aidx = (bky==-INFINITY)?0:r_ix[0];
      bool isv = aidx<VOCAB;
      int kcl = aidx-VOCAB; kcl = kcl<0?0:(kcl>(L-1)?(L-1):kcl);
      int sp = xt[kcl];
      int action = isv? aidx : sp;
      if(b==0){
        float prob = amask[aidx]*__expf(logits[aidx]-lmax)/Z;
        if(!isv){
          int a2 = action<0?0:(action>(VOCAB-1)?(VOCAB-1):action);
          prob += amask[a2]*__expf(logits[a2]-lmax)/Z;
        }
        out[65*1024 + (t-1)] = prob;
        out[65*1024 + 64 + (t-1)] = (float)action;
        *(int*)(ws+WS_ACT) = action;
      }
      s_lmax=lmax; s_Z=Z; s_act=action;
    }
  }
  __syncthreads();
  if(fin_only) return;

  const int action = s_act;
  if(b==0 && tid<64){
    int k=tid;
    float v=__expf(logits[VOCAB+k]-s_lmax)/s_Z;
    int sp=(k<L)? xt[k] : -1;
    float m=(k>=1 && k<(L-1) && sp!=action)?1.0f:0.0f;
    float pv=v*m;
    float s=wred_sum(pv);
    pcw[k]=(s>0.0f)? pv/s : pv;
  }
  {
    int row = action<0 ? action+VOCAB : action;
    const float* er = emb + (size_t)row*EMBED;
    const float* hp = h_dec + ((t-1)&1)*1024;
    for(int j=tid;j<1024;j+=256){ dec_in[j]=er[j]; hprev[j]=hp[j]; }
  }
  __syncthreads();
  {
    int r = b*4 + wave;
    const float* wr = attn_W + (size_t)r*2048;
    float acc=0.0f;
    #pragma unroll
    for(int c4=0;c4<4;c4++){
      int m=c4*256+lane*4;
      acc += d4(*(const float4*)(wr+m),      *(const float4*)(&dec_in[m]));
      acc += d4(*(const float4*)(wr+1024+m), *(const float4*)(&hprev[m]));
    }
    acc=wred_sum(acc);
    if(lane==0) attw_raw[r]=acc+attn_b[r];
  }
}

// ================= k_dec_gates5: lean GEMV — action/pc/attw precomputed by gen3 tail =================
__global__ __launch_bounds__(256) void k_dec_gates5(
  const float* __restrict__ emb,
  const float* __restrict__ Wih_d, const float* __restrict__ Whh_d,
  const float* __restrict__ bih_d, const float* __restrict__ bhh_d,
  float* __restrict__ ws, int t)
{
  __shared__ __align__(16) float di[1024];
  __shared__ __align__(16) float hh[1024];
  __shared__ float pcs[64], aws[64];
  const int tid=threadIdx.x, b=blockIdx.x, wave=tid>>6, lane=tid&63;
  float* h_dec=ws+WS_H_DEC; float* dg=ws+WS_DGATES;
  const float* G=ws+WS_G;
  if(t==0){
    for(int j=tid;j<1024;j+=256) di[j]=emb[j];       // sos
    if(tid<64){ pcs[tid]=0.0f; aws[tid]=0.0f; }
  } else {
    const int action = *(const int*)(ws+WS_ACT);
    const float* er = emb + (size_t)action*EMBED;
    for(int j=tid;j<1024;j+=256) di[j]=er[j];
    if(tid<64){ pcs[tid]=(ws+WS_PC)[tid]; aws[tid]=(ws+WS_ATTW)[tid]; }
  }
  {
    const float* hp=h_dec+((t+1)&1)*1024;   // h_{t-1}
    for(int j=tid;j<1024;j+=256) hh[j]=hp[j];
  }
  __syncthreads();
  for(int rr=0;rr<2;rr++){
    int r=b*8+wave*2+rr;
    const float* wd=Wih_d+(size_t)r*3072;
    float acc=0.0f;
    #pragma unroll
    for(int c4=0;c4<4;c4++){
      int m=c4*256+lane*4;
      acc += d4(*(const float4*)(wd+m), *(const float4*)(&di[m]));
    }
    const float* hr=Whh_d+(size_t)r*1024;
    #pragma unroll
    for(int c4=0;c4<4;c4++){
      int m=c4*256+lane*4;
      acc += d4(*(const float4*)(hr+m), *(const float4*)(&hh[m]));
    }
    acc += G[(size_t)r*64+lane]*pcs[lane];
    acc += G[(size_t)(4096+r)*64+lane]*aws[lane];
    acc=wred_sum(acc);
    if(lane==0) dg[r]=acc+bih_d[r]+bhh_d[r];
  }
}

// ================= k_dec_gates3 (round-8 fallback) =================
__global__ __launch_bounds__(256) void k_dec_gates3(
  const float* __restrict__ emb,
  const float* __restrict__ Wih_d, const float* __restrict__ Whh_d,
  const float* __restrict__ bih_d, const float* __restrict__ bhh_d,
  float* __restrict__ ws, int t)
{
  __shared__ __align__(16) float di[1024];
  __shared__ __align__(16) float hh[1024];
  __shared__ float pcs[64], aws[64];
  const int tid=threadIdx.x;
  float* h_dec=ws+WS_H_DEC; float* dg=ws+WS_DGATES;
  const float* G=ws+WS_G;
  if(t==0){
    for(int j=tid;j<1024;j+=256) di[j]=emb[j];
    if(tid<64){ pcs[tid]=0.0f; aws[tid]=0.0f; }
  } else {
    const int action = *(const int*)(ws+WS_ACT);
    const float* er = emb + (size_t)action*EMBED;
    for(int j=tid;j<1024;j+=256) di[j]=er[j];
    if(tid<64){
      pcs[tid]=(ws+WS_PC)[tid];
      float v=(ws+WS_ATTW)[tid];
      float mx=wred_max(v);
      float e=__expf(v-mx);
      float s=wred_sum(e);
      aws[tid]=e/s;
    }
  }
  {
    const float* hp=h_dec+((t+1)&1)*1024;
    for(int j=tid;j<1024;j+=256) hh[j]=hp[j];
  }
  __syncthreads();
  const int wave=tid>>6, lane=tid&63;
  for(int rr=0;rr<2;rr++){
    int r=blockIdx.x*8+wave*2+rr;
    const float* wd=Wih_d+(size_t)r*3072;
    float acc=0.0f;
    #pragma unroll
    for(int c4=0;c4<4;c4++){
      int m=c4*256+lane*4;
      acc += d4(*(const float4*)(wd+m), *(const float4*)(&di[m]));
    }
    const float* hr=Whh_d+(size_t)r*1024;
    #pragma unroll
    for(int c4=0;c4<4;c4++){
      int m=c4*256+lane*4;
      acc += d4(*(const float4*)(hr+m), *(const float4*)(&hh[m]));
    }
    acc += G[(size_t)r*64+lane]*pcs[lane];
    acc += G[(size_t)(4096+r)*64+lane]*aws[lane];
    acc=wred_sum(acc);
    if(lane==0) dg[r]=acc+bih_d[r]+bhh_d[r];
  }
}

// ================= k_dec_gen3: gen GEMV + A_h + ticket tail finalize =================
__global__ __launch_bounds__(256) void k_dec_gen3(
  const int* __restrict__ xt, const float* __restrict__ amask,
  const float* __restrict__ gen_W, const float* __restrict__ gen_b,
  const float* __restrict__ attn_W, const float* __restrict__ attn_b,
  float* __restrict__ ws, float* __restrict__ out, int t)
{
  __shared__ __align__(16) float h_lds[1024];
  __shared__ float w_lm[4], w_sm[4], w_ky[4];
  __shared__ int w_ix[4];
  __shared__ float r_lm[256], r_sm[256], r_ky[256];
  __shared__ int r_ix[256];
  __shared__ float s_lmax, s_Z;
  __shared__ int s_act, s_old;
  const int tid=threadIdx.x, b=blockIdx.x, wave=tid>>6, lane=tid&63;
  float* dg=ws+WS_DGATES;
  float* c_dec=ws+WS_C_DEC; float* h_dec=ws+WS_H_DEC;
  float* logits=ws+WS_LOGITS; float* parts=ws+WS_PARTS;
  float* cenc=ws+WS_COPY_ENC;
  {
    const float* cp=c_dec+((t+1)&1)*1024;
    float* cw=c_dec+(t&1)*1024;
    float* hw=h_dec+(t&1)*1024;
    for(int u=tid;u<1024;u+=256){
      float ig=dg[u], fg=dg[1024+u], gg=dg[2048+u], og=dg[3072+u];
      float c=sigm(fg)*cp[u]+sigm(ig)*tanhf(gg);
      float h=sigm(og)*tanhf(c);
      h_lds[u]=h;
      if(b==0){ cw[u]=c; hw[u]=h; out[(size_t)(t+1)*1024+u]=h; }
    }
  }
  __syncthreads();
  if(b==501){
    // A_h[r] = attn_W[r, 1024:2048] . h_t
    float* AH=ws+WS_AH;
    for(int rr=0;rr<16;rr++){
      int r=wave*16+rr;
      const float* wr = attn_W + (size_t)r*2048 + 1024;
      float acc=0.0f;
      #pragma unroll
      for(int c4=0;c4<4;c4++){
        int m=c4*256+lane*4;
        acc += d4(*(const float4*)(wr+m), *(const float4*)(&h_lds[m]));
      }
      acc=wred_sum(acc);
      if(lane==0) AH[r]=acc;
    }
  } else {
    const bool isGen=(b<500);
    const int rbase = isGen ? (b*64+wave*16) : (VOCAB+wave*16);
    float lv[16];
    #pragma unroll
    for(int rr=0;rr<16;rr++){
      const float* wr = isGen ? gen_W+(size_t)(rbase+rr)*1024
                              : cenc +(size_t)(rbase-VOCAB+rr)*1024;
      float acc=0.0f;
      #pragma unroll
      for(int c4=0;c4<4;c4++){
        int m=c4*256+lane*4;
        acc += d4(*(const float4*)(wr+m), *(const float4*)(&h_lds[m]));
      }
      acc=wred_sum(acc);
      lv[rr] = isGen ? acc+gen_b[rbase+rr] : acc;
    }
    if(lane==0){
      float lm=-INFINITY, ky=-INFINITY; int ix=0;
      #pragma unroll
      for(int rr=0;rr<16;rr++){
        int gi=rbase+rr;
        logits[gi]=lv[rr];
        lm=fmaxf(lm,lv[rr]);
        float mk=amask[gi];
        float kk = (mk>0.0f)? (lv[rr]+__logf(mk)) : -INFINITY;
        if(kk>ky){ ky=kk; ix=gi; }
      }
      float sm=0.0f;
      #pragma unroll
      for(int rr=0;rr<16;rr++) sm += __expf(lv[rr]-lm);
      w_lm[wave]=lm; w_sm[wave]=sm; w_ky[wave]=ky; w_ix[wave]=ix;
    }
    __syncthreads();
    if(tid==0){
      float lm=w_lm[0], sm=w_sm[0], ky=w_ky[0]; int ix=w_ix[0];
      for(int w=1;w<4;w++){
        float blm=w_lm[w], bsm=w_sm[w];
        if(blm>lm){ sm=sm*__expf(lm-blm)+bsm; lm=blm; }
        else sm += bsm*__expf(blm-lm);
        if(w_ky[w]>ky || (w_ky[w]==ky && w_ix[w]<ix)){ ky=w_ky[w]; ix=w_ix[w]; }
      }
      float4 p; p.x=lm; p.y=sm; p.z=ky; p.w=__int_as_float(ix);
      *(float4*)(parts+(size_t)b*4)=p;
    }
  }

  // ---- ticket: last block of 502 finalizes step t (round-2-proven pattern) ----
  __syncthreads();
  if(tid==0){
    __threadfence();
    s_old=__hip_atomic_fetch_add((int*)(ws+WS_TICK)+t,1,__ATOMIC_ACQ_REL,__HIP_MEMORY_SCOPE_AGENT);
  }
  __syncthreads();
  if(s_old!=(int)gridDim.x-1) return;
  if(tid==0) __threadfence();   // acquire: see all blocks' parts/AH writes
  __syncthreads();

  // finalize (round-4-proven reduce, identical math)
  {
    float lm=-INFINITY, sm=0.0f, ky=-INFINITY; int ix=0x7fffffff;
    for(int i=tid;i<NPART;i+=256){
      const float4 p = *(const float4*)(parts+(size_t)i*4);
      float plm=p.x, psm=p.y, pky=p.z; int pix=__float_as_int(p.w);
      if(plm>lm){ sm = sm*__expf(lm-plm)+psm; lm=plm; }
      else sm += psm*__expf(plm-lm);
      if(pky>ky || (pky==ky && pix<ix)){ ky=pky; ix=pix; }
    }
    r_lm[tid]=lm; r_sm[tid]=sm; r_ky[tid]=ky; r_ix[tid]=ix;
    __syncthreads();
    for(int s=128;s;s>>=1){
      if(tid<s){
        float blm=r_lm[tid+s], bsm=r_sm[tid+s];
        float alm=r_lm[tid], a_sm=r_sm[tid];
        if(blm>alm){ r_sm[tid]=a_sm*__expf(alm-blm)+bsm; r_lm[tid]=blm; }
        else r_sm[tid]=a_sm+bsm*__expf(blm-alm);
        float bky=r_ky[tid+s]; int bix=r_ix[tid+s];
        if(bky>r_ky[tid] || (bky==r_ky[tid] && bix<r_ix[tid])){ r_ky[tid]=bky; r_ix[tid]=bix; }
      }
      __syncthreads();
    }
    if(tid==0){
      float lmax=r_lm[0]; float Z=r_sm[0];
      float bky=r_ky[0];
      int aidx = (bky==-INFINITY)?0:r_ix[0];
      bool isv = aidx<VOCAB;
      int kcl = aidx-VOCAB; kcl = kcl<0?0:(kcl>(L-1)?(L-1):kcl);
      int sp = xt[kcl];
      int action = isv? aidx : sp;
      float prob = amask[aidx]*__expf(logits[aidx]-lmax)/Z;
      if(!isv){
        int a2 = action<0?0:(action>(VOCAB-1)?(VOCAB-1):action);
        prob += amask[a2]*__expf(logits[a2]-lmax)/Z;
      }
      out[65*1024 + t]      = prob;
      out[65*1024 + 64 + t] = (float)action;
      *(int*)(ws+WS_ACT) = action;
      s_lmax=lmax; s_Z=Z; s_act=action;
    }
  }
  __syncthreads();
  if(t==ML-1) return;
  const int action=s_act;
  if(tid<64){
    int k=tid;
    // pc (identical math)
    float v=__expf(logits[VOCAB+k]-s_lmax)/s_Z;
    int sp=(k<L)? xt[k] : -1;
    float m=(k>=1 && k<(L-1) && sp!=action)?1.0f:0.0f;
    float pv=v*m;
    float s=wred_sum(pv);
    (ws+WS_PC)[k]=(s>0.0f)? pv/s : pv;
    // attw = softmax( P[action][k] + A_h[k] + attn_b[k] ) (identical math)
    float raw = (ws+WS_P)[(size_t)action*64 + k] + (ws+WS_AH)[k] + attn_b[k];
    float mx=wred_max(raw);
    float e=__expf(raw-mx);
    float s2=wred_sum(e);
    (ws+WS_ATTW)[k]=e/s2;
  }
}

// ================= decoder gen v2 (fallback path) =================
__global__ __launch_bounds__(256) void k_dec_gen2(
  const float* __restrict__ gen_W, const float* __restrict__ gen_b,
  const float* __restrict__ amask, const float* __restrict__ attn_W,
  float* __restrict__ ws, float* __restrict__ out, int t)
{
  __shared__ __align__(16) float h_lds[1024];
  __shared__ float w_lm[4], w_sm[4], w_ky[4];
  __shared__ int w_ix[4];
  const int tid=threadIdx.x;
  float* dg=ws+WS_DGATES;
  float* c_dec=ws+WS_C_DEC; float* h_dec=ws+WS_H_DEC;
  float* logits=ws+WS_LOGITS; float* parts=ws+WS_PARTS;
  float* cenc=ws+WS_COPY_ENC;
  {
    const float* cp=c_dec+((t+1)&1)*1024;
    float* cw=c_dec+(t&1)*1024;
    float* hw=h_dec+(t&1)*1024;
    for(int u=tid;u<1024;u+=256){
      float ig=dg[u], fg=dg[1024+u], gg=dg[2048+u], og=dg[3072+u];
      float c=sigm(fg)*cp[u]+sigm(ig)*tanhf(gg);
      float h=sigm(og)*tanhf(c);
      h_lds[u]=h;
      if(blockIdx.x==0){ cw[u]=c; hw[u]=h; out[(size_t)(t+1)*1024+u]=h; }
    }
  }
  __syncthreads();
  const int wave=tid>>6, lane=tid&63;
  const int b=blockIdx.x;
  if(b==501){
    float* AH=ws+WS_AH;
    for(int rr=0;rr<16;rr++){
      int r=wave*16+rr;
      const float* wr = attn_W + (size_t)r*2048 + 1024;
      float acc=0.0f;
      #pragma unroll
      for(int c4=0;c4<4;c4++){
        int m=c4*256+lane*4;
        acc += d4(*(const float4*)(wr+m), *(const float4*)(&h_lds[m]));
      }
      acc=wred_sum(acc);
      if(lane==0) AH[r]=acc;
    }
    return;
  }
  const bool isGen=(b<500);
  const int rbase = isGen ? (b*64+wave*16) : (VOCAB+wave*16);
  float lv[16];
  #pragma unroll
  for(int rr=0;rr<16;rr++){
    const float* wr = isGen ? gen_W+(size_t)(rbase+rr)*1024
                            : cenc +(size_t)(rbase-VOCAB+rr)*1024;
    float acc=0.0f;
    #pragma unroll
    for(int c4=0;c4<4;c4++){
      int m=c4*256+lane*4;
      acc += d4(*(const float4*)(wr+m), *(const float4*)(&h_lds[m]));
    }
    acc=wred_sum(acc);
    lv[rr] = isGen ? acc+gen_b[rbase+rr] : acc;
  }
  if(lane==0){
    float lm=-INFINITY, ky=-INFINITY; int ix=0;
    #pragma unroll
    for(int rr=0;rr<16;rr++){
      int gi=rbase+rr;
      logits[gi]=lv[rr];
      lm=fmaxf(lm,lv[rr]);
      float mk=amask[gi];
      float kk = (mk>0.0f)? (lv[rr]+__logf(mk)) : -INFINITY;
      if(kk>ky){ ky=kk; ix=gi; }
    }
    float sm=0.0f;
    #pragma unroll
    for(int rr=0;rr<16;rr++) sm += __expf(lv[rr]-lm);
    w_lm[wave]=lm; w_sm[wave]=sm; w_ky[wave]=ky; w_ix[wave]=ix;
  }
  __syncthreads();
  if(tid==0){
    float lm=w_lm[0], sm=w_sm[0], ky=w_ky[0]; int ix=w_ix[0];
    for(int w=1;w<4;w++){
      float blm=w_lm[w], bsm=w_sm[w];
      if(blm>lm){ sm=sm*__expf(lm-blm)+bsm; lm=blm; }
      else sm += bsm*__expf(blm-lm);
      if(w_ky[w]>ky || (w_ky[w]==ky && w_ix[w]<ix)){ ky=w_ky[w]; ix=w_ix[w]; }
    }
    float4 p; p.x=lm; p.y=sm; p.z=ky; p.w=__int_as_float(ix);
    *(float4*)(parts+(size_t)b*4)=p;
  }
}

extern "C" void kernel_launch(void* const* d_in, const int* in_sizes, int n_in,
                              void* d_out, int out_size, void* d_ws, size_t ws_size,
                              hipStream_t stream)
{
  const int*   xt     = (const int*)d_in[0];
  const float* amask  = (const float*)d_in[1];
  const float* emb    = (const float*)d_in[2];
  const float* Wih_f  = (const float*)d_in[3];
  const float* Whh_f  = (const float*)d_in[4];
  const float* bih_f  = (const float*)d_in[5];
  const float* bhh_f  = (const float*)d_in[6];
  const float* Wih_b  = (const float*)d_in[7];
  const float* Whh_b  = (const float*)d_in[8];
  const float* bih_b  = (const float*)d_in[9];
  const float* bhh_b  = (const float*)d_in[10];
  const float* Wih_d  = (const float*)d_in[11];
  const float* Whh_d  = (const float*)d_in[12];
  const float* bih_d  = (const float*)d_in[13];
  const float* bhh_d  = (const float*)d_in[14];
  const float* attn_W = (const float*)d_in[15];
  const float* attn_b = (const float*)d_in[16];
  const float* gen_W  = (const float*)d_in[17];
  const float* gen_b  = (const float*)d_in[18];
  const float* copy_W = (const float*)d_in[19];
  const float* copy_b = (const float*)d_in[20];
  float* out=(float*)d_out;
  float* ws =(float*)d_ws;

  const bool hasPreg = ws_size >= (size_t)WS_PREG_END*sizeof(float);
  const bool hasP    = ws_size >= (size_t)WS_END3*sizeof(float);

  if(hasPreg){
    k_enc_pre2<<<512,256,0,stream>>>(xt,emb,Wih_f,bih_f,bhh_f,Wih_b,bih_b,bhh_b,ws);
    for(int t=0;t<L;t++)
      k_enc_rec<<<512,256,0,stream>>>(Whh_f,Whh_b,ws,t);
  } else {
    for(int t=0;t<L;t++)
      k_enc_step<<<512,256,0,stream>>>(xt,emb,Wih_f,Whh_f,bih_f,bhh_f,Wih_b,Whh_b,bih_b,bhh_b,ws,t);
  }
  k_copy_final<<<256,256,0,stream>>>(emb,copy_W,copy_b,ws,out);
  k_gmat3<<<512,256,0,stream>>>(Wih_d,ws);

  if(hasP){
    hipMemsetAsync((char*)d_ws + (size_t)WS_TICK*sizeof(float), 0, 64*sizeof(int), stream);
    k_pmat5<<<500,256,0,stream>>>(emb,attn_W,ws);
    for(int t=0;t<ML;t++){
      k_dec_gates5<<<512,256,0,stream>>>(emb,Wih_d,Whh_d,bih_d,bhh_d,ws,t);
      k_dec_gen3  <<<502,256,0,stream>>>(xt,amask,gen_W,gen_b,attn_W,attn_b,ws,out,t);
    }
  } else {
    k_dec_gates3<<<512,256,0,stream>>>(emb,Wih_d,Whh_d,bih_d,bhh_d,ws,0);
    k_dec_gen2  <<<501,256,0,stream>>>(gen_W,gen_b,amask,attn_W,ws,out,0);
    for(int t=1;t<ML;t++){
      k_fin16     <<<16,256,0,stream>>>(xt,amask,emb,attn_W,attn_b,ws,out,t,0);
      k_dec_gates3<<<512,256,0,stream>>>(emb,Wih_d,Whh_d,bih_d,bhh_d,ws,t);
      k_dec_gen2  <<<501,256,0,stream>>>(gen_W,gen_b,amask,attn_W,ws,out,t);
    }
    k_fin16<<<1,256,0,stream>>>(xt,amask,emb,attn_W,attn_b,ws,out,ML,1);
  }
}

// Round 15
// 3049.197 us; speedup vs baseline: 1.3561x; 1.3561x over previous
//
#include <hip/hip_runtime.h>
#include <math.h>

#define L 50
#define ML 64
#define VOCAB 32000
#define EMBED 1024
#define HID 1024
#define HH 512
#define TOT (VOCAB+ML)
#define NPART 501

// workspace layout (float offsets)
#define WS_ENC_GATES 0        // [2][4096]
#define WS_C_ENC     8192     // [2][1024]
#define WS_ENC_OUTS  10240    // [64][1024]
#define WS_COPY_ENC  75776    // [64][1024]
#define WS_H_DEC     141312   // [2][1024]
#define WS_C_DEC     143360   // [2][1024]
#define WS_X_DEC     145408   // [3072]
#define WS_DGATES    148480   // [4096]
#define WS_LOGITS    152576   // [32064]
#define WS_PARTS     184640   // [501*4] {lmax,sumexp,bestkey,bestidx}
#define WS_ATTW      186688   // [64] RAW attention logits (fallback path)
#define WS_PC        186752   // [64] selective-read weights
#define WS_ACT       186816   // [1] action
#define WS_G         186880   // [8192][64]: rows 0..4095 = G_sel, 4096..8191 = G_att
#define WS_G_END     (186880+8192*64)          // 711168
#define WS_PREG      711168   // [50][4096] encoder input-side pregates
#define WS_PREG_END  (711168+50*4096)          // 915968
#define WS_AH        915968   // [64] attn h-part logits
#define WS_P         916032   // [32000][64] attn emb-part logits
#define WS_P_END     (916032+32000*64)         // 2964032

__device__ __forceinline__ float wred_sum(float v){
  #pragma unroll
  for(int o=32;o;o>>=1) v += __shfl_xor(v,o,64);
  return v;
}
__device__ __forceinline__ float wred_max(float v){
  #pragma unroll
  for(int o=32;o;o>>=1) v = fmaxf(v,__shfl_xor(v,o,64));
  return v;
}
__device__ __forceinline__ float sigm(float x){ return 1.0f/(1.0f+__expf(-x)); }
__device__ __forceinline__ float d4(float4 a, float4 b){ return a.x*b.x + a.y*b.y + a.z*b.z + a.w*b.w; }

// ================= encoder pregates, barrier-free + next-row prefetch =================
__global__ __launch_bounds__(256) void k_enc_pre2(
  const int* __restrict__ xt, const float* __restrict__ emb,
  const float* __restrict__ Wih_f, const float* __restrict__ bih_f, const float* __restrict__ bhh_f,
  const float* __restrict__ Wih_b, const float* __restrict__ bih_b, const float* __restrict__ bhh_b,
  float* __restrict__ ws)
{
  __shared__ int toks[L];
  const int tid=threadIdx.x, b=blockIdx.x, wave=tid>>6, lane=tid&63;
  float* pg = ws + WS_PREG;
  if(tid<L) toks[tid]=xt[tid];
  float4 wih[2][4]; float bias[2];
  #pragma unroll
  for(int rr=0;rr<2;rr++){
    int r=b*8+wave*2+rr; bool isF=(r<2048); int rl=isF?r:(r-2048);
    const float* wp=(isF?Wih_f:Wih_b)+(size_t)rl*EMBED;
    #pragma unroll
    for(int c4=0;c4<4;c4++) wih[rr][c4]=*(const float4*)(wp+c4*256+lane*4);
    bias[rr]= isF?(bih_f[rl]+bhh_f[rl]):(bih_b[rl]+bhh_b[rl]);
  }
  __syncthreads();
  const float* er0 = emb + (size_t)toks[0]*EMBED;
  float4 e0=*(const float4*)(er0      +lane*4);
  float4 e1=*(const float4*)(er0+256  +lane*4);
  float4 e2=*(const float4*)(er0+512  +lane*4);
  float4 e3=*(const float4*)(er0+768  +lane*4);
  for(int t=0;t<L;t++){
    int tn = (t+1<L)? t+1 : t;
    const float* en = emb + (size_t)toks[tn]*EMBED;
    float4 n0=*(const float4*)(en      +lane*4);
    float4 n1=*(const float4*)(en+256  +lane*4);
    float4 n2=*(const float4*)(en+512  +lane*4);
    float4 n3=*(const float4*)(en+768  +lane*4);
    #pragma unroll
    for(int rr=0;rr<2;rr++){
      int r=b*8+wave*2+rr;
      float acc = d4(wih[rr][0],e0)+d4(wih[rr][1],e1)+d4(wih[rr][2],e2)+d4(wih[rr][3],e3);
      acc=wred_sum(acc);
      if(lane==0) pg[(size_t)t*4096+r]=acc+bias[rr];
    }
    e0=n0; e1=n1; e2=n2; e3=n3;
  }
}

// ================= encoder recurrent step =================
__global__ __launch_bounds__(256) void k_enc_rec(
  const float* __restrict__ Whh_f, const float* __restrict__ Whh_b,
  float* __restrict__ ws, int t)
{
  __shared__ __align__(16) float h_lds[1024];
  const int tid=threadIdx.x, b=blockIdx.x, wave=tid>>6, lane=tid&63;
  float* gates   = ws + WS_ENC_GATES;
  float* c_enc   = ws + WS_C_ENC;
  float* enc_outs= ws + WS_ENC_OUTS;
  const float* pg = ws + WS_PREG + (size_t)t*4096;
  if(t>0){
    const float* gp = gates + ((t-1)&1)*4096;
    const float* cp = c_enc + (t&1)*1024;
    float* cw = c_enc + ((t-1)&1)*1024;
    for(int u=tid;u<1024;u+=256){
      int base=(u<512)?0:2048, uu=(u<512)?u:(u-512);
      float ig=gp[base+uu], fg=gp[base+512+uu], gg=gp[base+1024+uu], og=gp[base+1536+uu];
      float cprev=(t==1)?0.0f:cp[u];
      float c=sigm(fg)*cprev+sigm(ig)*tanhf(gg);
      float h=sigm(og)*tanhf(c);
      h_lds[u]=h;
      if(b==0){ cw[u]=c; enc_outs[(size_t)(t-1)*1024+u]=h; }
    }
  }
  __syncthreads();
  float* gw = gates + (t&1)*4096;
  #pragma unroll
  for(int rr=0;rr<2;rr++){
    int r=b*8+wave*2+rr; bool isF=(r<2048); int rl=isF?r:(r-2048);
    if(t==0){
      if(lane==0) gw[r]=pg[r];
    } else {
      const float* hr=(isF?Whh_f:Whh_b)+(size_t)rl*HH;
      const float* hs=&h_lds[isF?0:512];
      float acc=0.0f;
      #pragma unroll
      for(int c2=0;c2<2;c2++){
        int m=c2*256+lane*4;
        acc += d4(*(const float4*)(hr+m), *(const float4*)(&hs[m]));
      }
      acc=wred_sum(acc);
      if(lane==0) gw[r]=pg[r]+acc;
    }
  }
}

// ================= fallback encoder step (round-4 proven) =================
__global__ __launch_bounds__(256) void k_enc_step(
  const int* __restrict__ xt, const float* __restrict__ emb,
  const float* __restrict__ Wih_f, const float* __restrict__ Whh_f,
  const float* __restrict__ bih_f, const float* __restrict__ bhh_f,
  const float* __restrict__ Wih_b, const float* __restrict__ Whh_b,
  const float* __restrict__ bih_b, const float* __restrict__ bhh_b,
  float* __restrict__ ws, int t)
{
  __shared__ __align__(16) float h_lds[1024];
  __shared__ __align__(16) float xe[1024];
  const int tid = threadIdx.x;
  float* gates   = ws + WS_ENC_GATES;
  float* c_enc   = ws + WS_C_ENC;
  float* enc_outs= ws + WS_ENC_OUTS;
  {
    const int tok = xt[t];
    const float* er = emb + (size_t)tok*EMBED;
    for(int j=tid;j<1024;j+=256) xe[j]=er[j];
  }
  if(t>0){
    const float* gp = gates + ((t-1)&1)*4096;
    const float* cp = c_enc + (t&1)*1024;
    float* cw = c_enc + ((t-1)&1)*1024;
    for(int u=tid;u<1024;u+=256){
      int base=(u<512)?0:2048, uu=(u<512)?u:(u-512);
      float ig=gp[base+uu], fg=gp[base+512+uu], gg=gp[base+1024+uu], og=gp[base+1536+uu];
      float cprev=(t==1)?0.0f:cp[u];
      float c=sigm(fg)*cprev+sigm(ig)*tanhf(gg);
      float h=sigm(og)*tanhf(c);
      h_lds[u]=h;
      if(blockIdx.x==0){ cw[u]=c; enc_outs[(size_t)(t-1)*1024+u]=h; }
    }
  }
  __syncthreads();
  float* gw = gates + (t&1)*4096;
  const int wave=tid>>6, lane=tid&63;
  for(int rr=0;rr<2;rr++){
    int r=blockIdx.x*8+wave*2+rr;
    bool isF=(r<2048); int rl=isF?r:(r-2048);
    const float* Wih=isF?Wih_f:Wih_b;
    const float* Whh=isF?Whh_f:Whh_b;
    float bias=isF?(bih_f[rl]+bhh_f[rl]):(bih_b[rl]+bhh_b[rl]);
    const float* wr=Wih+(size_t)rl*EMBED;
    float acc=0.0f;
    #pragma unroll
    for(int c4=0;c4<4;c4++){
      int m=c4*256+lane*4;
      acc += d4(*(const float4*)(wr+m), *(const float4*)(&xe[m]));
    }
    if(t>0){
      const float* hr=Whh+(size_t)rl*HH;
      const float* hs=&h_lds[isF?0:512];
      #pragma unroll
      for(int c2=0;c2<2;c2++){
        int m=c2*256+lane*4;
        acc += d4(*(const float4*)(hr+m), *(const float4*)(&hs[m]));
      }
    }
    acc=wred_sum(acc);
    if(lane==0) gw[r]=acc+bias;
  }
}

// ================= k_copy_final (round-5 proven) =================
__global__ __launch_bounds__(256) void k_copy_final(
  const float* __restrict__ emb,
  const float* __restrict__ copy_W, const float* __restrict__ copy_b,
  float* __restrict__ ws, float* __restrict__ out)
{
  __shared__ __align__(16) float hf[1024];
  const int tid=threadIdx.x, b=blockIdx.x, wave=tid>>6, lane=tid&63;
  float* gates = ws + WS_ENC_GATES;
  float* c_enc = ws + WS_C_ENC;
  float* enc_outs = ws + WS_ENC_OUTS;
  float* cenc = ws + WS_COPY_ENC;
  float* h_dec = ws + WS_H_DEC;
  float* c_dec = ws + WS_C_DEC;
  float* x_dec = ws + WS_X_DEC;
  {
    const float* gp = gates + ((L-1)&1)*4096;
    const float* cp = c_enc + ((L-2)&1)*1024;
    for(int u=tid;u<1024;u+=256){
      int base=(u<512)?0:2048, uu=(u<512)?u:(u-512);
      float ig=gp[base+uu], fg=gp[base+512+uu], gg=gp[base+1024+uu], og=gp[base+1536+uu];
      float c=sigm(fg)*cp[u]+sigm(ig)*tanhf(gg);
      float h=sigm(og)*tanhf(c);
      hf[u]=h;
      if(b==0){
        enc_outs[(size_t)(L-1)*1024+u]=h;
        h_dec[1024+u]=h;
        c_dec[1024+u]=c;
        out[u]=h;
      }
    }
    if(b==1) for(int j=tid;j<(ML-L)*1024;j+=256) enc_outs[(size_t)L*1024+j]=0.0f;
    if(b==2) for(int j=tid;j<1024;j+=256){
      x_dec[j]=emb[j];
      x_dec[1024+j]=0.0f;
      x_dec[2048+j]=0.0f;
    }
  }
  __syncthreads();
  int j = b*4 + wave;
  const float* wr = copy_W + (size_t)j*1024;
  float4 w0=*(const float4*)(wr+0*256+lane*4);
  float4 w1=*(const float4*)(wr+1*256+lane*4);
  float4 w2=*(const float4*)(wr+2*256+lane*4);
  float4 w3=*(const float4*)(wr+3*256+lane*4);
  float bj = copy_b[j];
  for(int k=0;k<L-1;k++){
    const float* er = enc_outs + (size_t)k*1024;
    float acc = d4(w0,*(const float4*)(er+0*256+lane*4))
              + d4(w1,*(const float4*)(er+1*256+lane*4))
              + d4(w2,*(const float4*)(er+2*256+lane*4))
              + d4(w3,*(const float4*)(er+3*256+lane*4));
    acc = wred_sum(acc);
    if(lane==0) cenc[(size_t)k*1024+j]=tanhf(acc+bj);
  }
  {
    float acc = d4(w0,*(const float4*)(&hf[0*256+lane*4]))
              + d4(w1,*(const float4*)(&hf[1*256+lane*4]))
              + d4(w2,*(const float4*)(&hf[2*256+lane*4]))
              + d4(w3,*(const float4*)(&hf[3*256+lane*4]));
    acc = wred_sum(acc);
    if(lane==0) cenc[(size_t)(L-1)*1024+j]=tanhf(acc+bj);
  }
  if(lane==0){
    float z=tanhf(0.0f+bj);
    for(int k=L;k<ML;k++) cenc[(size_t)k*1024+j]=z;
  }
}

// ================= k_gmat3: no-LDS, barrier-free, next-row prefetch =================
__global__ __launch_bounds__(256) void k_gmat3(const float* __restrict__ Wih_d, float* __restrict__ ws)
{
  const int tid=threadIdx.x, wave=tid>>6, lane=tid&63;
  const float* enc = ws + WS_ENC_OUTS;
  float* G = ws + WS_G;
  float4 w[4][4];
  int rg[4];
  #pragma unroll
  for(int q=0;q<4;q++){
    int r = blockIdx.x*16 + wave*4 + q;     // 0..8191
    rg[q]=r;
    const float* W = (r<4096) ? (Wih_d + (size_t)r*3072 + 1024)
                              : (Wih_d + (size_t)(r-4096)*3072 + 2048);
    #pragma unroll
    for(int c4=0;c4<4;c4++) w[q][c4]=*(const float4*)(W + c4*256 + lane*4);
  }
  const float* er0 = enc;
  float4 e0=*(const float4*)(er0      +lane*4);
  float4 e1=*(const float4*)(er0+256  +lane*4);
  float4 e2=*(const float4*)(er0+512  +lane*4);
  float4 e3=*(const float4*)(er0+768  +lane*4);
  for(int k=0;k<L;k++){
    int kn = (k+1<L)? k+1 : k;
    const float* en = enc + (size_t)kn*1024;
    float4 n0=*(const float4*)(en      +lane*4);
    float4 n1=*(const float4*)(en+256  +lane*4);
    float4 n2=*(const float4*)(en+512  +lane*4);
    float4 n3=*(const float4*)(en+768  +lane*4);
    #pragma unroll
    for(int q=0;q<4;q++){
      float acc = d4(w[q][0],e0)+d4(w[q][1],e1)+d4(w[q][2],e2)+d4(w[q][3],e3);
      acc=wred_sum(acc);
      if(lane==0) G[(size_t)rg[q]*64 + k]=acc;
    }
    e0=n0; e1=n1; e2=n2; e3=n3;
  }
  if(lane==0){
    #pragma unroll
    for(int q=0;q<4;q++)
      for(int kk=L;kk<64;kk++) G[(size_t)rg[q]*64 + kk]=0.0f;
  }
}

// ================= k_pmat5: tiled GEMM P = emb @ attn_W[:,0:1024]^T (round-13 proven) =================
__global__ __launch_bounds__(256) void k_pmat5(
  const float* __restrict__ emb, const float* __restrict__ attn_W, float* __restrict__ ws)
{
  __shared__ float e_lds[64][68];
  __shared__ float w_lds[64][68];
  const int tid=threadIdx.x;
  const int wq=tid>>4, rq=tid&15;
  float* P = ws + WS_P;
  const int w0 = blockIdx.x*64;
  float acc[4][4];
  #pragma unroll
  for(int i=0;i<4;i++)
    #pragma unroll
    for(int j=0;j<4;j++) acc[i][j]=0.0f;
  for(int kc=0;kc<16;kc++){
    __syncthreads();
    #pragma unroll
    for(int v=0;v<4;v++){
      int idx=(v*256+tid)*4;
      int row=idx>>6, col=idx&63;
      float4 te=*(const float4*)(emb    + (size_t)(w0+row)*EMBED + kc*64 + col);
      *(float4*)&e_lds[row][col]=te;
      float4 tw=*(const float4*)(attn_W + (size_t)row*2048      + kc*64 + col);
      *(float4*)&w_lds[row][col]=tw;
    }
    __syncthreads();
    #pragma unroll
    for(int k4=0;k4<16;k4++){
      float4 e4[4], w4[4];
      #pragma unroll
      for(int i=0;i<4;i++) e4[i]=*(const float4*)&e_lds[wq+i*16][k4*4];
      #pragma unroll
      for(int j=0;j<4;j++) w4[j]=*(const float4*)&w_lds[rq+j*16][k4*4];
      #pragma unroll
      for(int i=0;i<4;i++)
        #pragma unroll
        for(int j=0;j<4;j++){
          acc[i][j] += e4[i].x*w4[j].x;
          acc[i][j] += e4[i].y*w4[j].y;
          acc[i][j] += e4[i].z*w4[j].z;
          acc[i][j] += e4[i].w*w4[j].w;
        }
    }
  }
  #pragma unroll
  for(int i=0;i<4;i++)
    #pragma unroll
    for(int j=0;j<4;j++)
      P[(size_t)(w0+wq+i*16)*64 + rq+j*16] = acc[i][j];
}

// ================= k_fin16: finalize (fallback path + final-step tail) =================
__global__ __launch_bounds__(256) void k_fin16(
  const int* __restrict__ xt, const float* __restrict__ amask,
  const float* __restrict__ emb,
  const float* __restrict__ attn_W, const float* __restrict__ attn_b,
  float* __restrict__ ws, float* __restrict__ out, int t, int fin_only)
{
  __shared__ __align__(16) float dec_in[1024];
  __shared__ __align__(16) float hprev[1024];
  __shared__ float r_lm[256], r_sm[256], r_ky[256];
  __shared__ int r_ix[256];
  __shared__ float s_lmax, s_Z;
  __shared__ int s_act;
  const int tid=threadIdx.x, b=blockIdx.x, wave=tid>>6, lane=tid&63;
  float* h_dec=ws+WS_H_DEC;
  float* logits=ws+WS_LOGITS; float* parts=ws+WS_PARTS;
  float* attw_raw=ws+WS_ATTW; float* pcw=ws+WS_PC;
  {
    float lm=-INFINITY, sm=0.0f, ky=-INFINITY; int ix=0x7fffffff;
    for(int i=tid;i<NPART;i+=256){
      const float4 p = *(const float4*)(parts+(size_t)i*4);
      float plm=p.x, psm=p.y, pky=p.z; int pix=__float_as_int(p.w);
      if(plm>lm){ sm = sm*__expf(lm-plm)+psm; lm=plm; }
      else sm += psm*__expf(plm-lm);
      if(pky>ky || (pky==ky && pix<ix)){ ky=pky; ix=pix; }
    }
    r_lm[tid]=lm; r_sm[tid]=sm; r_ky[tid]=ky; r_ix[tid]=ix;
    __syncthreads();
    for(int s=128;s;s>>=1){
      if(tid<s){
        float blm=r_lm[tid+s], bsm=r_sm[tid+s];
        float alm=r_lm[tid], a_sm=r_sm[tid];
        if(blm>alm){ r_sm[tid]=a_sm*__expf(alm-blm)+bsm; r_lm[tid]=blm; }
        else r_sm[tid]=a_sm+bsm*__expf(blm-alm);
        float bky=r_ky[tid+s]; int bix=r_ix[tid+s];
        if(bky>r_ky[tid] || (bky==r_ky[tid] && bix<r_ix[tid])){ r_ky[tid]=bky; r_ix[tid]=bix; }
      }
      __syncthreads();
    }
    if(tid==0){
      float lmax=r_lm[0]; float Z=r_sm[0];
      float bky=r_ky[0];
      int aidx = (bky==-INFINITY)?0:r_ix[0];
      bool isv = aidx<VOCAB;
      int kcl = aidx-VOCAB; kcl = kcl<0?0:(kcl>(L-1)?(L-1):kcl);
      int sp = xt[kcl];
      int action = isv? aidx : sp;
      if(b==0){
        float prob = amask[aidx]*__expf(logits[aidx]-lmax)/Z;
        if(!isv){
          int a2 = action<0?0:(action>(VOCAB-1)?(VOCAB-1):action);
          prob += amask[a2]*__expf(logits[a2]-lmax)/Z;
        }
        out[65*1024 + (t-1)] = prob;
        out[65*1024 + 64 + (t-1)] = (float)action;
        *(int*)(ws+WS_ACT) = action;
      }
      s_lmax=lmax; s_Z=Z; s_act=action;
    }
  }
  __syncthreads();
  if(fin_only) return;

  const int action = s_act;
  if(b==0 && tid<64){
    int k=tid;
    float v=__expf(logits[VOCAB+k]-s_lmax)/s_Z;
    int sp=(k<L)? xt[k] : -1;
    float m=(k>=1 && k<(L-1) && sp!=action)?1.0f:0.0f;
    float pv=v*m;
    float s=wred_sum(pv);
    pcw[k]=(s>0.0f)? pv/s : pv;
  }
  {
    int row = action<0 ? action+VOCAB : action;
    const float* er = emb + (size_t)row*EMBED;
    const float* hp = h_dec + ((t-1)&1)*1024;
    for(int j=tid;j<1024;j+=256){ dec_in[j]=er[j]; hprev[j]=hp[j]; }
  }
  __syncthreads();
  {
    int r = b*4 + wave;
    const float* wr = attn_W + (size_t)r*2048;
    float acc=0.0f;
    #pragma unroll
    for(int c4=0;c4<4;c4++){
      int m=c4*256+lane*4;
      acc += d4(*(const float4*)(wr+m),      *(const float4*)(&dec_in[m]));
      acc += d4(*(const float4*)(wr+1024+m), *(const float4*)(&hprev[m]));
    }
    acc=wred_sum(acc);
    if(lane==0) attw_raw[r]=acc+attn_b[r];
  }
}

// ================= k_dec_gates4: fin-prologue (shuffle reduce, 1 barrier) + attw via P/A_h + G-GEMV =================
__global__ __launch_bounds__(256) void k_dec_gates4(
  const int* __restrict__ xt, const float* __restrict__ amask,
  const float* __restrict__ emb, const float* __restrict__ attn_b,
  const float* __restrict__ Wih_d, const float* __restrict__ Whh_d,
  const float* __restrict__ bih_d, const float* __restrict__ bhh_d,
  float* __restrict__ ws, float* __restrict__ out, int t)
{
  __shared__ __align__(16) float di[1024];
  __shared__ __align__(16) float hh[1024];
  __shared__ float pcs[64], aws[64];
  __shared__ float w_lm[4], w_sm[4], w_ky[4];
  __shared__ int w_ix[4];
  __shared__ float s_lmax, s_Z;
  __shared__ int s_act;
  const int tid=threadIdx.x, b=blockIdx.x, wave=tid>>6, lane=tid&63;
  float* h_dec=ws+WS_H_DEC; float* dg=ws+WS_DGATES;
  float* logits=ws+WS_LOGITS; float* parts=ws+WS_PARTS;
  const float* G=ws+WS_G;

  if(t==0){
    for(int j=tid;j<1024;j+=256) di[j]=emb[j];       // sos
    if(tid<64){ pcs[tid]=0.0f; aws[tid]=0.0f; }
    __syncthreads();
  } else {
    // ---- finalize step t-1: per-thread strided accumulate + wave butterfly + 4-way combine ----
    float lm=-INFINITY, sm=0.0f, ky=-INFINITY; int ix=0x7fffffff;
    for(int i=tid;i<NPART;i+=256){
      const float4 p = *(const float4*)(parts+(size_t)i*4);
      float plm=p.x, psm=p.y, pky=p.z; int pix=__float_as_int(p.w);
      if(plm>lm){ sm = sm*__expf(lm-plm)+psm; lm=plm; }
      else sm += psm*__expf(plm-lm);
      if(pky>ky || (pky==ky && pix<ix)){ ky=pky; ix=pix; }
    }
    // wave butterfly (symmetric combine; argmax exact, sm reorder ~1e-7)
    #pragma unroll
    for(int o=32;o;o>>=1){
      float blm=__shfl_xor(lm,o,64), bsm=__shfl_xor(sm,o,64);
      float bky=__shfl_xor(ky,o,64); int bix=__shfl_xor(ix,o,64);
      if(blm>lm){ sm=sm*__expf(lm-blm)+bsm; lm=blm; }
      else sm += bsm*__expf(blm-lm);
      if(bky>ky || (bky==ky && bix<ix)){ ky=bky; ix=bix; }
    }
    if(lane==0){ w_lm[wave]=lm; w_sm[wave]=sm; w_ky[wave]=ky; w_ix[wave]=ix; }
    __syncthreads();
    if(tid==0){
      float lm2=w_lm[0], sm2=w_sm[0], ky2=w_ky[0]; int ix2=w_ix[0];
      for(int w=1;w<4;w++){
        float blm=w_lm[w], bsm=w_sm[w];
        if(blm>lm2){ sm2=sm2*__expf(lm2-blm)+bsm; lm2=blm; }
        else sm2 += bsm*__expf(blm-lm2);
        if(w_ky[w]>ky2 || (w_ky[w]==ky2 && w_ix[w]<ix2)){ ky2=w_ky[w]; ix2=w_ix[w]; }
      }
      float lmax=lm2, Z=sm2;
      int aidx = (ky2==-INFINITY)?0:ix2;
      bool isv = aidx<VOCAB;
      int kcl = aidx-VOCAB; kcl = kcl<0?0:(kcl>(L-1)?(L-1):kcl);
      int sp = xt[kcl];
      int action = isv? aidx : sp;
      if(b==0){
        float prob = amask[aidx]*__expf(logits[aidx]-lmax)/Z;
        if(!isv){
          int a2 = action<0?0:(action>(VOCAB-1)?(VOCAB-1):action);
          prob += amask[a2]*__expf(logits[a2]-lmax)/Z;
        }
        out[65*1024 + (t-1)] = prob;
        out[65*1024 + 64 + (t-1)] = (float)action;
      }
      s_lmax=lmax; s_Z=Z; s_act=action;
    }
    __syncthreads();
    const int action = s_act;
    // pc (identical math)
    if(tid<64){
      int k=tid;
      float v=__expf(logits[VOCAB+k]-s_lmax)/s_Z;
      int sp=(k<L)? xt[k] : -1;
      float m=(k>=1 && k<(L-1) && sp!=action)?1.0f:0.0f;
      float pv=v*m;
      float s=wred_sum(pv);
      pcs[k]=(s>0.0f)? pv/s : pv;
    }
    // attw = softmax( P[action][k] + A_h[k] + attn_b[k] )
    if(tid>=64 && tid<128){
      int k=tid-64;
      float raw = (ws+WS_P)[(size_t)action*64 + k] + (ws+WS_AH)[k] + attn_b[k];
      float mx=wred_max(raw);
      float e=__expf(raw-mx);
      float s=wred_sum(e);
      aws[k]=e/s;
    }
    // dec_in
    {
      const float* er = emb + (size_t)action*EMBED;
      for(int j=tid;j<1024;j+=256) di[j]=er[j];
    }
    __syncthreads();
  }
  {
    const float* hp=h_dec+((t+1)&1)*1024;   // h_{t-1}
    for(int j=tid;j<1024;j+=256) hh[j]=hp[j];
  }
  __syncthreads();
  for(int rr=0;rr<2;rr++){
    int r=b*8+wave*2+rr;
    const float* wd=Wih_d+(size_t)r*3072;
    float acc=0.0f;
    #pragma unroll
    for(int c4=0;c4<4;c4++){
      int m=c4*256+lane*4;
      acc += d4(*(const float4*)(wd+m), *(const float4*)(&di[m]));
    }
    const float* hr=Whh_d+(size_t)r*1024;
    #pragma unroll
    for(int c4=0;c4<4;c4++){
      int m=c4*256+lane*4;
      acc += d4(*(const float4*)(hr+m), *(const float4*)(&hh[m]));
    }
    acc += G[(size_t)r*64+lane]*pcs[lane];
    acc += G[(size_t)(4096+r)*64+lane]*aws[lane];
    acc=wred_sum(acc);
    if(lane==0) dg[r]=acc+bih_d[r]+bhh_d[r];
  }
}

// ================= k_dec_gates3 (round-8 fallback) =================
__global__ __launch_bounds__(256) void k_dec_gates3(
  const float* __restrict__ emb,
  const float* __restrict__ Wih_d, const float* __restrict__ Whh_d,
  const float* __restrict__ bih_d, const float* __restrict__ bhh_d,
  float* __restrict__ ws, int t)
{
  __shared__ __align__(16) float di[1024];
  __shared__ __align__(16) float hh[1024];
  __shared__ float pcs[64], aws[64];
  const int tid=threadIdx.x;
  float* h_dec=ws+WS_H_DEC; float* dg=ws+WS_DGATES;
  const float* G=ws+WS_G;
  if(t==0){
    for(int j=tid;j<1024;j+=256) di[j]=emb[j];
    if(tid<64){ pcs[tid]=0.0f; aws[tid]=0.0f; }
  } else {
    const int action = *(const int*)(ws+WS_ACT);
    const float* er = emb + (size_t)action*EMBED;
    for(int j=tid;j<1024;j+=256) di[j]=er[j];
    if(tid<64){
      pcs[tid]=(ws+WS_PC)[tid];
      float v=(ws+WS_ATTW)[tid];
      float mx=wred_max(v);
      float e=__expf(v-mx);
      float s=wred_sum(e);
      aws[tid]=e/s;
    }
  }
  {
    const float* hp=h_dec+((t+1)&1)*1024;
    for(int j=tid;j<1024;j+=256) hh[j]=hp[j];
  }
  __syncthreads();
  const int wave=tid>>6, lane=tid&63;
  for(int rr=0;rr<2;rr++){
    int r=blockIdx.x*8+wave*2+rr;
    const float* wd=Wih_d+(size_t)r*3072;
    float acc=0.0f;
    #pragma unroll
    for(int c4=0;c4<4;c4++){
      int m=c4*256+lane*4;
      acc += d4(*(const float4*)(wd+m), *(const float4*)(&di[m]));
    }
    const float* hr=Whh_d+(size_t)r*1024;
    #pragma unroll
    for(int c4=0;c4<4;c4++){
      int m=c4*256+lane*4;
      acc += d4(*(const float4*)(hr+m), *(const float4*)(&hh[m]));
    }
    acc += G[(size_t)r*64+lane]*pcs[lane];
    acc += G[(size_t)(4096+r)*64+lane]*aws[lane];
    acc=wred_sum(acc);
    if(lane==0) dg[r]=acc+bih_d[r]+bhh_d[r];
  }
}

// ================= decoder gen v2: +block 501 computes A_h = attn_Wh @ h_t =================
__global__ __launch_bounds__(256) void k_dec_gen2(
  const float* __restrict__ gen_W, const float* __restrict__ gen_b,
  const float* __restrict__ amask, const float* __restrict__ attn_W,
  float* __restrict__ ws, float* __restrict__ out, int t)
{
  __shared__ __align__(16) float h_lds[1024];
  __shared__ float w_lm[4], w_sm[4], w_ky[4];
  __shared__ int w_ix[4];
  const int tid=threadIdx.x;
  float* dg=ws+WS_DGATES;
  float* c_dec=ws+WS_C_DEC; float* h_dec=ws+WS_H_DEC;
  float* logits=ws+WS_LOGITS; float* parts=ws+WS_PARTS;
  float* cenc=ws+WS_COPY_ENC;
  {
    const float* cp=c_dec+((t+1)&1)*1024;
    float* cw=c_dec+(t&1)*1024;
    float* hw=h_dec+(t&1)*1024;
    for(int u=tid;u<1024;u+=256){
      float ig=dg[u], fg=dg[1024+u], gg=dg[2048+u], og=dg[3072+u];
      float c=sigm(fg)*cp[u]+sigm(ig)*tanhf(gg);
      float h=sigm(og)*tanhf(c);
      h_lds[u]=h;
      if(blockIdx.x==0){ cw[u]=c; hw[u]=h; out[(size_t)(t+1)*1024+u]=h; }
    }
  }
  __syncthreads();
  const int wave=tid>>6, lane=tid&63;
  const int b=blockIdx.x;
  if(b==501){
    float* AH=ws+WS_AH;
    for(int rr=0;rr<16;rr++){
      int r=wave*16+rr;
      const float* wr = attn_W + (size_t)r*2048 + 1024;
      float acc=0.0f;
      #pragma unroll
      for(int c4=0;c4<4;c4++){
        int m=c4*256+lane*4;
        acc += d4(*(const float4*)(wr+m), *(const float4*)(&h_lds[m]));
      }
      acc=wred_sum(acc);
      if(lane==0) AH[r]=acc;
    }
    return;
  }
  const bool isGen=(b<500);
  const int rbase = isGen ? (b*64+wave*16) : (VOCAB+wave*16);
  float lv[16];
  #pragma unroll
  for(int rr=0;rr<16;rr++){
    const float* wr = isGen ? gen_W+(size_t)(rbase+rr)*1024
                            : cenc +(size_t)(rbase-VOCAB+rr)*1024;
    float acc=0.0f;
    #pragma unroll
    for(int c4=0;c4<4;c4++){
      int m=c4*256+lane*4;
      acc += d4(*(const float4*)(wr+m), *(const float4*)(&h_lds[m]));
    }
    acc=wred_sum(acc);
    lv[rr] = isGen ? acc+gen_b[rbase+rr] : acc;
  }
  if(lane==0){
    float lm=-INFINITY, ky=-INFINITY; int ix=0;
    #pragma unroll
    for(int rr=0;rr<16;rr++){
      int gi=rbase+rr;
      logits[gi]=lv[rr];
      lm=fmaxf(lm,lv[rr]);
      float mk=amask[gi];
      float kk = (mk>0.0f)? (lv[rr]+__logf(mk)) : -INFINITY;
      if(kk>ky){ ky=kk; ix=gi; }
    }
    float sm=0.0f;
    #pragma unroll
    for(int rr=0;rr<16;rr++) sm += __expf(lv[rr]-lm);
    w_lm[wave]=lm; w_sm[wave]=sm; w_ky[wave]=ky; w_ix[wave]=ix;
  }
  __syncthreads();
  if(tid==0){
    float lm=w_lm[0], sm=w_sm[0], ky=w_ky[0]; int ix=w_ix[0];
    for(int w=1;w<4;w++){
      float blm=w_lm[w], bsm=w_sm[w];
      if(blm>lm){ sm=sm*__expf(lm-blm)+bsm; lm=blm; }
      else sm += bsm*__expf(blm-lm);
      if(w_ky[w]>ky || (w_ky[w]==ky && w_ix[w]<ix)){ ky=w_ky[w]; ix=w_ix[w]; }
    }
    float4 p; p.x=lm; p.y=sm; p.z=ky; p.w=__int_as_float(ix);
    *(float4*)(parts+(size_t)blockIdx.x*4)=p;
  }
}

extern "C" void kernel_launch(void* const* d_in, const int* in_sizes, int n_in,
                              void* d_out, int out_size, void* d_ws, size_t ws_size,
                              hipStream_t stream)
{
  const int*   xt     = (const int*)d_in[0];
  const float* amask  = (const float*)d_in[1];
  const float* emb    = (const float*)d_in[2];
  const float* Wih_f  = (const float*)d_in[3];
  const float* Whh_f  = (const float*)d_in[4];
  const float* bih_f  = (const float*)d_in[5];
  const float* bhh_f  = (const float*)d_in[6];
  const float* Wih_b  = (const float*)d_in[7];
  const float* Whh_b  = (const float*)d_in[8];
  const float* bih_b  = (const float*)d_in[9];
  const float* bhh_b  = (const float*)d_in[10];
  const float* Wih_d  = (const float*)d_in[11];
  const float* Whh_d  = (const float*)d_in[12];
  const float* bih_d  = (const float*)d_in[13];
  const float* bhh_d  = (const float*)d_in[14];
  const float* attn_W = (const float*)d_in[15];
  const float* attn_b = (const float*)d_in[16];
  const float* gen_W  = (const float*)d_in[17];
  const float* gen_b  = (const float*)d_in[18];
  const float* copy_W = (const float*)d_in[19];
  const float* copy_b = (const float*)d_in[20];
  float* out=(float*)d_out;
  float* ws =(float*)d_ws;

  const bool hasPreg = ws_size >= (size_t)WS_PREG_END*sizeof(float);
  const bool hasP    = ws_size >= (size_t)WS_P_END*sizeof(float);

  if(hasPreg){
    k_enc_pre2<<<512,256,0,stream>>>(xt,emb,Wih_f,bih_f,bhh_f,Wih_b,bih_b,bhh_b,ws);
    for(int t=0;t<L;t++)
      k_enc_rec<<<512,256,0,stream>>>(Whh_f,Whh_b,ws,t);
  } else {
    for(int t=0;t<L;t++)
      k_enc_step<<<512,256,0,stream>>>(xt,emb,Wih_f,Whh_f,bih_f,bhh_f,Wih_b,Whh_b,bih_b,bhh_b,ws,t);
  }
  k_copy_final<<<256,256,0,stream>>>(emb,copy_W,copy_b,ws,out);
  k_gmat3<<<512,256,0,stream>>>(Wih_d,ws);

  if(hasP){
    k_pmat5<<<500,256,0,stream>>>(emb,attn_W,ws);
    for(int t=0;t<ML;t++){
      k_dec_gates4<<<512,256,0,stream>>>(xt,amask,emb,attn_b,Wih_d,Whh_d,bih_d,bhh_d,ws,out,t);
      k_dec_gen2  <<<502,256,0,stream>>>(gen_W,gen_b,amask,attn_W,ws,out,t);
    }
    k_fin16<<<1,256,0,stream>>>(xt,amask,emb,attn_W,attn_b,ws,out,ML,1);
  } else {
    k_dec_gates3<<<512,256,0,stream>>>(emb,Wih_d,Whh_d,bih_d,bhh_d,ws,0);
    k_dec_gen2  <<<501,256,0,stream>>>(gen_W,gen_b,amask,attn_W,ws,out,0);
    for(int t=1;t<ML;t++){
      k_fin16     <<<16,256,0,stream>>>(xt,amask,emb,attn_W,attn_b,ws,out,t,0);
      k_dec_gates3<<<512,256,0,stream>>>(emb,Wih_d,Whh_d,bih_d,bhh_d,ws,t);
      k_dec_gen2  <<<501,256,0,stream>>>(gen_W,gen_b,amask,attn_W,ws,out,t);
    }
    k_fin16<<<1,256,0,stream>>>(xt,amask,emb,attn_W,attn_b,ws,out,ML,1);
  }
}